// Round 22
// baseline (138.497 us; speedup 1.0000x reference)
//
#include <hip/hip_runtime.h>
#include <hip/hip_bf16.h>

#define HDIM 768
#define NH 12
#define HD 64
#define BB 8
#define SS 1024
#define MROWS (BB*SS)      // 8192
#define NQKV (3*HDIM)      // 2304
#define GK 768
#define NGRAN 96           // 768/8 granules per row

#define SCL2E 0.18033688011f      // 0.125 * log2e
#define MASKNEG -14426.9504f      // -10000 * log2e

typedef __attribute__((ext_vector_type(8))) short bf16x8;
typedef __attribute__((ext_vector_type(4))) float f32x4;

__device__ __forceinline__ unsigned short f2bf(float f) {
    unsigned int u = __float_as_uint(f);
    unsigned int r = (u + 0x7fffu + ((u >> 16) & 1u)) >> 16;   // RNE
    return (unsigned short)r;
}

__device__ __forceinline__ void gload_lds16(const void* gsrc, void* ldst) {
    __builtin_amdgcn_global_load_lds(
        (const __attribute__((address_space(1))) unsigned int*)gsrc,
        (__attribute__((address_space(3))) unsigned int*)ldst,
        16, 0, 0);
}

// ---------------- fused pack kernel ----------------
// fm layout: fm[((row>>4)*96 + (k>>3))*128 + (row&15)*8 + (k&7)] = X[row][k]
// units: xb-fm 786432 (row,g) | wqkv-fm 221184 | wo plain 147456 float4
__global__ void pack_all(const float* __restrict__ x,
                         const float* __restrict__ Wq, const float* __restrict__ Wk,
                         const float* __restrict__ Wv, const float* __restrict__ Wo,
                         const float* __restrict__ bq, const float* __restrict__ bk,
                         const float* __restrict__ bv, const int* __restrict__ m,
                         unsigned short* __restrict__ xbf, unsigned short* __restrict__ wqkvf,
                         unsigned short* __restrict__ wo,
                         float* __restrict__ biasq, float* __restrict__ madd)
{
    const int tid = blockIdx.x * blockDim.x + threadIdx.x;
    const int stride = gridDim.x * blockDim.x;
    for (int i = tid; i < 1155072; i += stride) {
        if (i < 1007616) {
            int row, g;
            const float* srcrow;
            unsigned short* dst;
            if (i < 786432) {                 // x -> xbf
                row = i / NGRAN; g = i - row * NGRAN;
                srcrow = x + (size_t)row * GK;
                dst = xbf;
            } else {                          // Wq/Wk/Wv -> wqkvf
                int j = i - 786432;
                row = j / NGRAN; g = j - row * NGRAN;
                int which = row / HDIM, rr = row - which * HDIM;
                srcrow = ((which == 0) ? Wq : (which == 1) ? Wk : Wv) + (size_t)rr * GK;
                dst = wqkvf;
            }
            float4 v0 = *(const float4*)(srcrow + g * 8);
            float4 v1 = *(const float4*)(srcrow + g * 8 + 4);
            unsigned long long q0 =
                (unsigned long long)f2bf(v0.x) | ((unsigned long long)f2bf(v0.y) << 16)
              | ((unsigned long long)f2bf(v0.z) << 32) | ((unsigned long long)f2bf(v0.w) << 48);
            unsigned long long q1 =
                (unsigned long long)f2bf(v1.x) | ((unsigned long long)f2bf(v1.y) << 16)
              | ((unsigned long long)f2bf(v1.z) << 32) | ((unsigned long long)f2bf(v1.w) << 48);
            unsigned long long* p = (unsigned long long*)
                (dst + ((size_t)(row >> 4) * NGRAN + g) * 128 + (row & 15) * 8);
            p[0] = q0; p[1] = q1;
        } else {                              // Wo plain row-major bf16
            int off = i - 1007616;
            float4 v = reinterpret_cast<const float4*>(Wo)[off];
            union { unsigned short u[4]; unsigned long long q; } o;
            o.u[0] = f2bf(v.x); o.u[1] = f2bf(v.y); o.u[2] = f2bf(v.z); o.u[3] = f2bf(v.w);
            reinterpret_cast<unsigned long long*>(wo)[off] = o.q;
        }
    }
    if (tid < 3 * HDIM)
        biasq[tid] = (tid < HDIM) ? bq[tid] : (tid < 2 * HDIM) ? bk[tid - HDIM] : bv[tid - 2 * HDIM];
    if (tid < BB * SS)
        madd[tid] = (m[tid] == 0) ? MASKNEG : 0.0f;
}

// ---------------- flat QKV GEMM: fragment-major direct loads, NO LDS, NO barriers ------
// 4 waves (2Mx2N), per-wave 64x64 out (acc[4][4]); per K-tile 16 coalesced 16B frag
// loads (L1/L2-served) + 32 MFMA. Grid 64x18=1152, XCD-swizzled. (256,3): ~143 regs.
__global__ __launch_bounds__(256, 3)
void gemm_flat(const unsigned short* __restrict__ Af,
               const unsigned short* __restrict__ Bf,
               const float* __restrict__ bias,
               unsigned short* __restrict__ qb,
               unsigned short* __restrict__ kb,
               unsigned short* __restrict__ vtb)
{
    const int tid  = threadIdx.x;
    const int wave = tid >> 6;
    const int lane = tid & 63;

    const int nwg = gridDim.x;              // 1152
    const int cpx = nwg >> 3;
    const int wg  = (blockIdx.x & 7) * cpx + (blockIdx.x >> 3);
    const int bm = (wg / 18) * 128;
    const int bn = (wg % 18) * 128;

    const int wm = (wave >> 1) * 64;
    const int wn = (wave & 1) * 64;
    const int lr = lane & 15;
    const int hv = lane >> 4;

    const unsigned short* Abase = Af + ((size_t)((bm + wm) >> 4) * NGRAN) * 128 + hv * 128 + lr * 8;
    const unsigned short* Bbase = Bf + ((size_t)((bn + wn) >> 4) * NGRAN) * 128 + hv * 128 + lr * 8;

    f32x4 zero4 = {0.f, 0.f, 0.f, 0.f};
    f32x4 acc[4][4];
#pragma unroll
    for (int i = 0; i < 4; i++)
#pragma unroll
        for (int j = 0; j < 4; j++) acc[i][j] = zero4;

    for (int t = 0; t < 12; ++t) {
        bf16x8 af[4][2], bf[4][2];
#pragma unroll
        for (int mi = 0; mi < 4; mi++)
#pragma unroll
            for (int kk = 0; kk < 2; kk++)
                af[mi][kk] = *(const bf16x8*)(Abase + ((size_t)mi * NGRAN + t * 8 + kk * 4) * 128);
#pragma unroll
        for (int ni = 0; ni < 4; ni++)
#pragma unroll
            for (int kk = 0; kk < 2; kk++)
                bf[ni][kk] = *(const bf16x8*)(Bbase + ((size_t)ni * NGRAN + t * 8 + kk * 4) * 128);

        __builtin_amdgcn_s_setprio(1);
#pragma unroll
        for (int kk = 0; kk < 2; kk++)
#pragma unroll
            for (int mi = 0; mi < 4; mi++)
#pragma unroll
                for (int ni = 0; ni < 4; ni++)
                    acc[mi][ni] = __builtin_amdgcn_mfma_f32_16x16x32_bf16(
                        af[mi][kk], bf[ni][kk], acc[mi][ni], 0, 0, 0);
        __builtin_amdgcn_s_setprio(0);
    }

    const int rgrp = lane >> 4;
#pragma unroll
    for (int mi = 0; mi < 4; mi++)
#pragma unroll
        for (int ni = 0; ni < 4; ni++)
#pragma unroll
            for (int r = 0; r < 4; r++) {
                int m = bm + wm + mi * 16 + rgrp * 4 + r;
                int n = bn + wn + ni * 16 + lr;
                float v = acc[mi][ni][r] + bias[n];
                int which = n / HDIM;
                int nn = n - which * HDIM;
                int h = nn >> 6, d = nn & 63;
                int b = m >> 10, s = m & 1023;
                unsigned short bvv = f2bf(v);
                if (which == 0)      qb [(((size_t)(b * NH + h)) * SS + s) * HD + d] = bvv;
                else if (which == 1) kb [(((size_t)(b * NH + h)) * SS + s) * HD + d] = bvv;
                else                 vtb[(((size_t)(b * NH + h)) * HD + d) * SS + s] = bvv;
            }
}

// ---------------- proj GEMM (R20-exact): 8 waves, 128x128, BK=64 dbuf, counted vmcnt ------
__global__ __launch_bounds__(512)
void gemm_bt(const unsigned short* __restrict__ A,
             const unsigned short* __restrict__ Bw,
             const float* __restrict__ bias,
             float* __restrict__ fout,
             int K, int gridN)
{
    __shared__ unsigned short As[2][128 * 64];
    __shared__ unsigned short Bs[2][128 * 64];
    const int tid  = threadIdx.x;
    const int wave = tid >> 6;
    const int lane = tid & 63;

    const int nwg = gridDim.x;
    const int cpx = nwg >> 3;
    const int wg  = (blockIdx.x & 7) * cpx + (blockIdx.x >> 3);
    const int bm = (wg / gridN) * 128;
    const int bn = (wg % gridN) * 128;

    const int wm = (wave >> 2) * 64;
    const int wn = (wave & 3) * 32;
    const int lr  = lane & 15;
    const int hv  = lane >> 4;
    const int e3  = lr & 7;
    const int srow = lane >> 3;
    const int sg   = lane & 7;

    f32x4 zero4 = {0.f, 0.f, 0.f, 0.f};
    f32x4 acc[4][2];
#pragma unroll
    for (int i = 0; i < 4; i++)
#pragma unroll
        for (int j = 0; j < 2; j++) acc[i][j] = zero4;

    auto stage = [&](int buf, int k0) {
        const int gk = (sg ^ srow) * 8;
#pragma unroll
        for (int jj = 0; jj < 2; ++jj) {
            int i = wave * 2 + jj;
            gload_lds16(A  + (size_t)(bm + i * 8 + srow) * K + k0 + gk, &As[buf][i * 8 * 64]);
            gload_lds16(Bw + (size_t)(bn + i * 8 + srow) * K + k0 + gk, &Bs[buf][i * 8 * 64]);
        }
    };

    stage(0, 0);
    if (K > 64) stage(1, 64);

    int buf = 0;
    for (int k0 = 0; k0 < K; k0 += 64) {
        if (k0 + 64 < K) { asm volatile("s_waitcnt vmcnt(4)" ::: "memory"); }
        else             { asm volatile("s_waitcnt vmcnt(0)" ::: "memory"); }
        __builtin_amdgcn_s_barrier();
        __builtin_amdgcn_sched_barrier(0);   // rule #18

        bf16x8 af[4][2], bf[2][2];
#pragma unroll
        for (int mi = 0; mi < 4; mi++)
#pragma unroll
            for (int kk = 0; kk < 2; kk++)
                af[mi][kk] = *(const bf16x8*)
                    &As[buf][(wm + mi * 16 + lr) * 64 + ((kk * 4 + hv) ^ e3) * 8];
#pragma unroll
        for (int ni = 0; ni < 2; ni++)
#pragma unroll
            for (int kk = 0; kk < 2; kk++)
                bf[ni][kk] = *(const bf16x8*)
                    &Bs[buf][(wn + ni * 16 + lr) * 64 + ((kk * 4 + hv) ^ e3) * 8];

        __builtin_amdgcn_s_setprio(1);
#pragma unroll
        for (int kk = 0; kk < 2; kk++)
#pragma unroll
            for (int mi = 0; mi < 4; mi++)
#pragma unroll
                for (int ni = 0; ni < 2; ni++)
                    acc[mi][ni] = __builtin_amdgcn_mfma_f32_16x16x32_bf16(
                        af[mi][kk], bf[ni][kk], acc[mi][ni], 0, 0, 0);
        __builtin_amdgcn_s_setprio(0);

        __builtin_amdgcn_s_barrier();
        if (k0 + 128 < K) stage(buf, k0 + 128);
        buf ^= 1;
    }

    const int rgrp = lane >> 4;
#pragma unroll
    for (int mi = 0; mi < 4; mi++)
#pragma unroll
        for (int ni = 0; ni < 2; ni++)
#pragma unroll
            for (int r = 0; r < 4; r++) {
                int m = bm + wm + mi * 16 + rgrp * 4 + r;
                int n = bn + wn + ni * 16 + lr;
                fout[(size_t)m * HDIM + n] = acc[mi][ni][r] + bias[n];
            }
}

// ---------------- flash attention: R20-exact (4 waves x 32 q, reuse, (256,3)) ----------------
__global__ __launch_bounds__(256, 3)
void attn_kernel(const unsigned short* __restrict__ qb,
                 const unsigned short* __restrict__ kb,
                 const unsigned short* __restrict__ vtb,
                 const float* __restrict__ maskadd,
                 unsigned short* __restrict__ ctx)
{
    __shared__ unsigned short Ks[64][64];
    __shared__ unsigned short Vs[64][64];
    __shared__ unsigned short Ps[4][32][64];

    const int tid  = threadIdx.x;
    const int wave = tid >> 6;
    const int lane = tid & 63;
    const int wg = (blockIdx.x & 7) * 96 + (blockIdx.x >> 3);
    const int qt = wg & 7;
    const int h  = (wg >> 3) % NH;
    const int b  = wg / 96;
    const int bh = b * NH + h;
    const int q0 = qt * 128 + wave * 32;
    const int lr  = lane & 15;
    const int hi  = lane >> 4;
    const int e3  = lr & 7;
    const int srow = lane >> 3;
    const int sg   = lane & 7;

    const unsigned short* Qp = qb  + (size_t)bh * SS * HD;
    const unsigned short* Kp = kb  + (size_t)bh * SS * HD;
    const unsigned short* Vp = vtb + (size_t)bh * HD * SS;
    const float* madd = maskadd + b * SS;

    bf16x8 aq[2][2];
#pragma unroll
    for (int g = 0; g < 2; g++)
#pragma unroll
        for (int kk = 0; kk < 2; kk++)
            aq[g][kk] = *(const bf16x8*)&Qp[(size_t)(q0 + g * 16 + lr) * HD + kk * 32 + hi * 8];

    f32x4 zero4 = {0.f, 0.f, 0.f, 0.f};
    f32x4 o[2][4];
#pragma unroll
    for (int g = 0; g < 2; g++)
#pragma unroll
        for (int i = 0; i < 4; i++) o[g][i] = zero4;
    float plsum0 = 0.f, plsum1 = 0.f;

    bf16x8 kreg[2], vreg[2];
    auto ld = [&](int t0) {
#pragma unroll
        for (int jj = 0; jj < 2; ++jj) {
            int rr = (wave * 2 + jj) * 8 + srow;
            kreg[jj] = *(const bf16x8*)&Kp[(size_t)(t0 + rr) * HD + sg * 8];
            vreg[jj] = *(const bf16x8*)&Vp[(size_t)rr * SS + t0 + sg * 8];
        }
    };
    auto wr = [&]() {
        const int slot = (sg ^ srow) * 8;
#pragma unroll
        for (int jj = 0; jj < 2; ++jj) {
            int rr = (wave * 2 + jj) * 8 + srow;
            *(bf16x8*)&Ks[rr][slot] = kreg[jj];
            *(bf16x8*)&Vs[rr][slot] = vreg[jj];
        }
    };

    ld(0);
    wr();
    __syncthreads();

    for (int t0 = 0; t0 < SS; t0 += 64) {
        const bool more = (t0 + 64 < SS);
        if (more) ld(t0 + 64);

        f32x4 sacc[2][4];
#pragma unroll
        for (int g = 0; g < 2; g++)
#pragma unroll
            for (int ni = 0; ni < 4; ni++) sacc[g][ni] = zero4;
        __builtin_amdgcn_s_setprio(1);
#pragma unroll
        for (int kk = 0; kk < 2; kk++)
#pragma unroll
            for (int ni = 0; ni < 4; ni++) {
                bf16x8 kf = *(const bf16x8*)&Ks[ni * 16 + lr][((kk * 4 + hi) ^ e3) * 8];
                sacc[0][ni] = __builtin_amdgcn_mfma_f32_16x16x32_bf16(kf, aq[0][kk], sacc[0][ni], 0, 0, 0);
                sacc[1][ni] = __builtin_amdgcn_mfma_f32_16x16x32_bf16(kf, aq[1][kk], sacc[1][ni], 0, 0, 0);
            }
        __builtin_amdgcn_s_setprio(0);

        float4 md[4];
#pragma unroll
        for (int ni = 0; ni < 4; ni++)
            md[ni] = *(const float4*)&madd[t0 + ni * 16 + hi * 4];

#pragma unroll
        for (int ni = 0; ni < 4; ni++) {
            float p0 = __builtin_amdgcn_exp2f(fmaf(sacc[0][ni][0], SCL2E, md[ni].x));
            float p1 = __builtin_amdgcn_exp2f(fmaf(sacc[0][ni][1], SCL2E, md[ni].y));
            float p2 = __builtin_amdgcn_exp2f(fmaf(sacc[0][ni][2], SCL2E, md[ni].z));
            float p3 = __builtin_amdgcn_exp2f(fmaf(sacc[0][ni][3], SCL2E, md[ni].w));
            plsum0 += p0 + p1 + p2 + p3;
            union { __hip_bfloat162 h2[2]; unsigned long long q; } u;
            u.h2[0] = __float22bfloat162_rn(make_float2(p0, p1));
            u.h2[1] = __float22bfloat162_rn(make_float2(p2, p3));
            *(unsigned long long*)&Ps[wave][lr][((4 * ni + hi) ^ (e3 << 1)) * 4] = u.q;
        }
#pragma unroll
        for (int ni = 0; ni < 4; ni++) {
            float p0 = __builtin_amdgcn_exp2f(fmaf(sacc[1][ni][0], SCL2E, md[ni].x));
            float p1 = __builtin_amdgcn_exp2f(fmaf(sacc[1][ni][1], SCL2E, md[ni].y));
            float p2 = __builtin_amdgcn_exp2f(fmaf(sacc[1][ni][2], SCL2E, md[ni].z));
            float p3 = __builtin_amdgcn_exp2f(fmaf(sacc[1][ni][3], SCL2E, md[ni].w));
            plsum1 += p0 + p1 + p2 + p3;
            union { __hip_bfloat162 h2[2]; unsigned long long q; } u;
            u.h2[0] = __float22bfloat162_rn(make_float2(p0, p1));
            u.h2[1] = __float22bfloat162_rn(make_float2(p2, p3));
            *(unsigned long long*)&Ps[wave][16 + lr][((4 * ni + hi) ^ (e3 << 1)) * 4] = u.q;
        }

        __builtin_amdgcn_s_setprio(1);
#pragma unroll
        for (int ks = 0; ks < 2; ks++) {
            bf16x8 pa0 = *(const bf16x8*)&Ps[wave][lr]     [((8 * ks + 2 * hi) ^ (e3 << 1)) * 4];
            bf16x8 pa1 = *(const bf16x8*)&Ps[wave][16 + lr][((8 * ks + 2 * hi) ^ (e3 << 1)) * 4];
#pragma unroll
            for (int nd = 0; nd < 4; nd++) {
                bf16x8 vb = *(const bf16x8*)&Vs[nd * 16 + lr][((4 * ks + hi) ^ e3) * 8];
                o[0][nd] = __builtin_amdgcn_mfma_f32_16x16x32_bf16(pa0, vb, o[0][nd], 0, 0, 0);
                o[1][nd] = __builtin_amdgcn_mfma_f32_16x16x32_bf16(pa1, vb, o[1][nd], 0, 0, 0);
            }
        }
        __builtin_amdgcn_s_setprio(0);

        __syncthreads();
        if (more) {
            wr();
            __syncthreads();
        }
    }

#pragma unroll
    for (int g = 0; g < 2; g++) {
        float lrun = (g == 0) ? plsum0 : plsum1;
        lrun += __shfl_xor(lrun, 16);
        lrun += __shfl_xor(lrun, 32);
        float iv[4];
#pragma unroll
        for (int r = 0; r < 4; r++) iv[r] = 1.0f / __shfl(lrun, hi * 4 + r, 16);
#pragma unroll
        for (int r = 0; r < 4; r++) {
            int grow = b * SS + q0 + g * 16 + hi * 4 + r;
#pragma unroll
            for (int nd = 0; nd < 4; nd++)
                ctx[(size_t)grow * HDIM + h * HD + nd * 16 + lr] =
                    f2bf(((g == 0) ? o[0][nd][r] : o[1][nd][r]) * iv[r]);
        }
    }
}

// ---------------- launch ----------------
extern "C" void kernel_launch(void* const* d_in, const int* in_sizes, int n_in,
                              void* d_out, int out_size, void* d_ws, size_t ws_size,
                              hipStream_t stream)
{
    const float* x    = (const float*)d_in[0];
    const int*   amask= (const int*)d_in[1];
    const float* Wq   = (const float*)d_in[2];
    const float* bq   = (const float*)d_in[3];
    const float* Wk   = (const float*)d_in[4];
    const float* bk   = (const float*)d_in[5];
    const float* Wv   = (const float*)d_in[6];
    const float* bv   = (const float*)d_in[7];
    const float* Wo   = (const float*)d_in[8];
    const float* bo   = (const float*)d_in[9];
    float* out = (float*)d_out;

    char* ws = (char*)d_ws;
    unsigned short* xbf  = (unsigned short*)(ws);                   // 12582912 (fm)
    unsigned short* wqkvf= (unsigned short*)(ws + 12582912);        // 3538944 (fm)
    unsigned short* wo   = (unsigned short*)(ws + 16121856);        // 1179648
    float*          biasq= (float*)(ws + 17301504);                 // 9216
    unsigned short* qb   = (unsigned short*)(ws + 17310720);        // 12582912
    unsigned short* kb   = (unsigned short*)(ws + 29893632);        // 12582912
    unsigned short* vtb  = (unsigned short*)(ws + 42476544);        // 12582912
    unsigned short* ctx  = (unsigned short*)(ws + 55059456);        // 12582912
    float*          madd = (float*)(ws + 67642368);                 // 32768 -> ends 67675136

    pack_all<<<2048, 256, 0, stream>>>(x, Wq, Wk, Wv, Wo, bq, bk, bv, amask,
                                       xbf, wqkvf, wo, biasq, madd);

    gemm_flat<<<(MROWS / 128) * (NQKV / 128), 256, 0, stream>>>(
        xbf, wqkvf, biasq, qb, kb, vtb);

    attn_kernel<<<(SS / 128) * NH * BB, 256, 0, stream>>>(qb, kb, vtb, madd, ctx);

    gemm_bt<<<(MROWS / 128) * (HDIM / 128), 512, 0, stream>>>(
        ctx, wo, bo, out, GK, HDIM / 128);
}

// Round 23
// 128.840 us; speedup vs baseline: 1.0749x; 1.0749x over previous
//
#include <hip/hip_runtime.h>
#include <hip/hip_bf16.h>

#define HDIM 768
#define NH 12
#define HD 64
#define BB 8
#define SS 1024
#define MROWS (BB*SS)      // 8192
#define NQKV (3*HDIM)      // 2304
#define GK 768

#define SCL2E 0.18033688011f      // 0.125 * log2e
#define MASKNEG -14426.9504f      // -10000 * log2e

typedef __attribute__((ext_vector_type(8))) short bf16x8;
typedef __attribute__((ext_vector_type(4))) float f32x4;

__device__ __forceinline__ unsigned short f2bf(float f) {
    unsigned int u = __float_as_uint(f);
    unsigned int r = (u + 0x7fffu + ((u >> 16) & 1u)) >> 16;   // RNE
    return (unsigned short)r;
}

__device__ __forceinline__ void gload_lds16(const void* gsrc, void* ldst) {
    __builtin_amdgcn_global_load_lds(
        (const __attribute__((address_space(1))) unsigned int*)gsrc,
        (__attribute__((address_space(3))) unsigned int*)ldst,
        16, 0, 0);
}

// ---------------- fused pack kernel ----------------
__global__ void pack_all(const float* __restrict__ x,
                         const float* __restrict__ Wq, const float* __restrict__ Wk,
                         const float* __restrict__ Wv, const float* __restrict__ Wo,
                         const float* __restrict__ bq, const float* __restrict__ bk,
                         const float* __restrict__ bv, const int* __restrict__ m,
                         unsigned short* __restrict__ xb, unsigned short* __restrict__ wqkv,
                         unsigned short* __restrict__ wo,
                         float* __restrict__ biasq, float* __restrict__ madd)
{
    const int tid = blockIdx.x * blockDim.x + threadIdx.x;
    const int stride = gridDim.x * blockDim.x;
    for (int i = tid; i < 2162688; i += stride) {
        const float* src; unsigned short* dst; int off;
        if (i < 1572864) { src = x; dst = xb; off = i; }
        else {
            int j = i - 1572864;
            int seg = j / 147456;
            off = j - seg * 147456;
            src = (seg == 0) ? Wq : (seg == 1) ? Wk : (seg == 2) ? Wv : Wo;
            dst = (seg == 3) ? wo : wqkv + seg * (HDIM * HDIM);
        }
        float4 v = reinterpret_cast<const float4*>(src)[off];
        union { unsigned short u[4]; unsigned long long q; } o;
        o.u[0] = f2bf(v.x); o.u[1] = f2bf(v.y); o.u[2] = f2bf(v.z); o.u[3] = f2bf(v.w);
        reinterpret_cast<unsigned long long*>(dst)[off] = o.q;
    }
    if (tid < 3 * HDIM)
        biasq[tid] = (tid < HDIM) ? bq[tid] : (tid < 2 * HDIM) ? bk[tid - HDIM] : bv[tid - 2 * HDIM];
    if (tid < BB * SS)
        madd[tid] = (m[tid] == 0) ? MASKNEG : 0.0f;
}

// ---------------- GEMM (R19/R20-exact): 8 waves, BK=64 dbuf, counted vmcnt, T2 swizzle ------
template<int MODE>
__global__ __launch_bounds__(512)
void gemm_bt(const unsigned short* __restrict__ A,
             const unsigned short* __restrict__ Bw,
             const float* __restrict__ bias,
             unsigned short* __restrict__ qb,
             unsigned short* __restrict__ kb,
             unsigned short* __restrict__ vtb,
             float* __restrict__ fout,
             int K, int gridN)
{
    __shared__ unsigned short As[2][128 * 64];
    __shared__ unsigned short Bs[2][128 * 64];
    const int tid  = threadIdx.x;
    const int wave = tid >> 6;          // 0..7
    const int lane = tid & 63;

    const int nwg = gridDim.x;
    const int cpx = nwg >> 3;
    const int wg  = (blockIdx.x & 7) * cpx + (blockIdx.x >> 3);
    const int bm = (wg / gridN) * 128;
    const int bn = (wg % gridN) * 128;

    const int wm = (wave >> 2) * 64;    // 0 / 64
    const int wn = (wave & 3) * 32;     // 0 / 32 / 64 / 96
    const int lr  = lane & 15;
    const int hv  = lane >> 4;
    const int e3  = lr & 7;
    const int srow = lane >> 3;
    const int sg   = lane & 7;

    f32x4 zero4 = {0.f, 0.f, 0.f, 0.f};
    f32x4 acc[4][2];
#pragma unroll
    for (int i = 0; i < 4; i++)
#pragma unroll
        for (int j = 0; j < 2; j++) acc[i][j] = zero4;

    auto stage = [&](int buf, int k0) {
        const int gk = (sg ^ srow) * 8;
#pragma unroll
        for (int jj = 0; jj < 2; ++jj) {
            int i = wave * 2 + jj;
            gload_lds16(A  + (size_t)(bm + i * 8 + srow) * K + k0 + gk, &As[buf][i * 8 * 64]);
            gload_lds16(Bw + (size_t)(bn + i * 8 + srow) * K + k0 + gk, &Bs[buf][i * 8 * 64]);
        }
    };

    stage(0, 0);
    if (K > 64) stage(1, 64);

    int buf = 0;
    for (int k0 = 0; k0 < K; k0 += 64) {
        if (k0 + 64 < K) { asm volatile("s_waitcnt vmcnt(4)" ::: "memory"); }
        else             { asm volatile("s_waitcnt vmcnt(0)" ::: "memory"); }
        __builtin_amdgcn_s_barrier();
        __builtin_amdgcn_sched_barrier(0);   // rule #18

        bf16x8 af[4][2], bf[2][2];
#pragma unroll
        for (int mi = 0; mi < 4; mi++)
#pragma unroll
            for (int kk = 0; kk < 2; kk++)
                af[mi][kk] = *(const bf16x8*)
                    &As[buf][(wm + mi * 16 + lr) * 64 + ((kk * 4 + hv) ^ e3) * 8];
#pragma unroll
        for (int ni = 0; ni < 2; ni++)
#pragma unroll
            for (int kk = 0; kk < 2; kk++)
                bf[ni][kk] = *(const bf16x8*)
                    &Bs[buf][(wn + ni * 16 + lr) * 64 + ((kk * 4 + hv) ^ e3) * 8];

        __builtin_amdgcn_s_setprio(1);
#pragma unroll
        for (int kk = 0; kk < 2; kk++)
#pragma unroll
            for (int mi = 0; mi < 4; mi++)
#pragma unroll
                for (int ni = 0; ni < 2; ni++)
                    acc[mi][ni] = __builtin_amdgcn_mfma_f32_16x16x32_bf16(
                        af[mi][kk], bf[ni][kk], acc[mi][ni], 0, 0, 0);
        __builtin_amdgcn_s_setprio(0);

        __builtin_amdgcn_s_barrier();
        if (k0 + 128 < K) stage(buf, k0 + 128);
        buf ^= 1;
    }

    const int rgrp = lane >> 4;
#pragma unroll
    for (int mi = 0; mi < 4; mi++)
#pragma unroll
        for (int ni = 0; ni < 2; ni++)
#pragma unroll
            for (int r = 0; r < 4; r++) {
                int m = bm + wm + mi * 16 + rgrp * 4 + r;
                int n = bn + wn + ni * 16 + lr;
                float v = acc[mi][ni][r] + bias[n];
                if (MODE == 0) {
                    int which = n / HDIM;
                    int nn = n - which * HDIM;
                    int h = nn >> 6, d = nn & 63;
                    int b = m >> 10, s = m & 1023;
                    unsigned short bvv = f2bf(v);
                    if (which == 0)      qb [(((size_t)(b * NH + h)) * SS + s) * HD + d] = bvv;
                    else if (which == 1) kb [(((size_t)(b * NH + h)) * SS + s) * HD + d] = bvv;
                    else                 vtb[(((size_t)(b * NH + h)) * HD + d) * SS + s] = bvv;
                } else {
                    fout[(size_t)m * HDIM + n] = v;
                }
            }
}

// ---------------- flash attention: R20-exact (4 waves x 32 q, reuse, (256,3)) ----------------
__global__ __launch_bounds__(256, 3)
void attn_kernel(const unsigned short* __restrict__ qb,
                 const unsigned short* __restrict__ kb,
                 const unsigned short* __restrict__ vtb,
                 const float* __restrict__ maskadd,
                 unsigned short* __restrict__ ctx)
{
    __shared__ unsigned short Ks[64][64];
    __shared__ unsigned short Vs[64][64];
    __shared__ unsigned short Ps[4][32][64];

    const int tid  = threadIdx.x;
    const int wave = tid >> 6;
    const int lane = tid & 63;
    const int wg = (blockIdx.x & 7) * 96 + (blockIdx.x >> 3);
    const int qt = wg & 7;
    const int h  = (wg >> 3) % NH;
    const int b  = wg / 96;
    const int bh = b * NH + h;
    const int q0 = qt * 128 + wave * 32;
    const int lr  = lane & 15;
    const int hi  = lane >> 4;
    const int e3  = lr & 7;
    const int srow = lane >> 3;
    const int sg   = lane & 7;

    const unsigned short* Qp = qb  + (size_t)bh * SS * HD;
    const unsigned short* Kp = kb  + (size_t)bh * SS * HD;
    const unsigned short* Vp = vtb + (size_t)bh * HD * SS;
    const float* madd = maskadd + b * SS;

    bf16x8 aq[2][2];
#pragma unroll
    for (int g = 0; g < 2; g++)
#pragma unroll
        for (int kk = 0; kk < 2; kk++)
            aq[g][kk] = *(const bf16x8*)&Qp[(size_t)(q0 + g * 16 + lr) * HD + kk * 32 + hi * 8];

    f32x4 zero4 = {0.f, 0.f, 0.f, 0.f};
    f32x4 o[2][4];
#pragma unroll
    for (int g = 0; g < 2; g++)
#pragma unroll
        for (int i = 0; i < 4; i++) o[g][i] = zero4;
    float plsum0 = 0.f, plsum1 = 0.f;

    bf16x8 kreg[2], vreg[2];
    auto ld = [&](int t0) {
#pragma unroll
        for (int jj = 0; jj < 2; ++jj) {
            int rr = (wave * 2 + jj) * 8 + srow;
            kreg[jj] = *(const bf16x8*)&Kp[(size_t)(t0 + rr) * HD + sg * 8];
            vreg[jj] = *(const bf16x8*)&Vp[(size_t)rr * SS + t0 + sg * 8];
        }
    };
    auto wr = [&]() {
        const int slot = (sg ^ srow) * 8;
#pragma unroll
        for (int jj = 0; jj < 2; ++jj) {
            int rr = (wave * 2 + jj) * 8 + srow;
            *(bf16x8*)&Ks[rr][slot] = kreg[jj];
            *(bf16x8*)&Vs[rr][slot] = vreg[jj];
        }
    };

    ld(0);
    wr();
    __syncthreads();

    for (int t0 = 0; t0 < SS; t0 += 64) {
        const bool more = (t0 + 64 < SS);
        if (more) ld(t0 + 64);

        f32x4 sacc[2][4];
#pragma unroll
        for (int g = 0; g < 2; g++)
#pragma unroll
            for (int ni = 0; ni < 4; ni++) sacc[g][ni] = zero4;
        __builtin_amdgcn_s_setprio(1);
#pragma unroll
        for (int kk = 0; kk < 2; kk++)
#pragma unroll
            for (int ni = 0; ni < 4; ni++) {
                bf16x8 kf = *(const bf16x8*)&Ks[ni * 16 + lr][((kk * 4 + hi) ^ e3) * 8];
                sacc[0][ni] = __builtin_amdgcn_mfma_f32_16x16x32_bf16(kf, aq[0][kk], sacc[0][ni], 0, 0, 0);
                sacc[1][ni] = __builtin_amdgcn_mfma_f32_16x16x32_bf16(kf, aq[1][kk], sacc[1][ni], 0, 0, 0);
            }
        __builtin_amdgcn_s_setprio(0);

        float4 md[4];
#pragma unroll
        for (int ni = 0; ni < 4; ni++)
            md[ni] = *(const float4*)&madd[t0 + ni * 16 + hi * 4];

#pragma unroll
        for (int ni = 0; ni < 4; ni++) {
            float p0 = __builtin_amdgcn_exp2f(fmaf(sacc[0][ni][0], SCL2E, md[ni].x));
            float p1 = __builtin_amdgcn_exp2f(fmaf(sacc[0][ni][1], SCL2E, md[ni].y));
            float p2 = __builtin_amdgcn_exp2f(fmaf(sacc[0][ni][2], SCL2E, md[ni].z));
            float p3 = __builtin_amdgcn_exp2f(fmaf(sacc[0][ni][3], SCL2E, md[ni].w));
            plsum0 += p0 + p1 + p2 + p3;
            union { __hip_bfloat162 h2[2]; unsigned long long q; } u;
            u.h2[0] = __float22bfloat162_rn(make_float2(p0, p1));
            u.h2[1] = __float22bfloat162_rn(make_float2(p2, p3));
            *(unsigned long long*)&Ps[wave][lr][((4 * ni + hi) ^ (e3 << 1)) * 4] = u.q;
        }
#pragma unroll
        for (int ni = 0; ni < 4; ni++) {
            float p0 = __builtin_amdgcn_exp2f(fmaf(sacc[1][ni][0], SCL2E, md[ni].x));
            float p1 = __builtin_amdgcn_exp2f(fmaf(sacc[1][ni][1], SCL2E, md[ni].y));
            float p2 = __builtin_amdgcn_exp2f(fmaf(sacc[1][ni][2], SCL2E, md[ni].z));
            float p3 = __builtin_amdgcn_exp2f(fmaf(sacc[1][ni][3], SCL2E, md[ni].w));
            plsum1 += p0 + p1 + p2 + p3;
            union { __hip_bfloat162 h2[2]; unsigned long long q; } u;
            u.h2[0] = __float22bfloat162_rn(make_float2(p0, p1));
            u.h2[1] = __float22bfloat162_rn(make_float2(p2, p3));
            *(unsigned long long*)&Ps[wave][16 + lr][((4 * ni + hi) ^ (e3 << 1)) * 4] = u.q;
        }

        __builtin_amdgcn_s_setprio(1);
#pragma unroll
        for (int ks = 0; ks < 2; ks++) {
            bf16x8 pa0 = *(const bf16x8*)&Ps[wave][lr]     [((8 * ks + 2 * hi) ^ (e3 << 1)) * 4];
            bf16x8 pa1 = *(const bf16x8*)&Ps[wave][16 + lr][((8 * ks + 2 * hi) ^ (e3 << 1)) * 4];
#pragma unroll
            for (int nd = 0; nd < 4; nd++) {
                bf16x8 vb = *(const bf16x8*)&Vs[nd * 16 + lr][((4 * ks + hi) ^ e3) * 8];
                o[0][nd] = __builtin_amdgcn_mfma_f32_16x16x32_bf16(pa0, vb, o[0][nd], 0, 0, 0);
                o[1][nd] = __builtin_amdgcn_mfma_f32_16x16x32_bf16(pa1, vb, o[1][nd], 0, 0, 0);
            }
        }
        __builtin_amdgcn_s_setprio(0);

        __syncthreads();
        if (more) {
            wr();
            __syncthreads();
        }
    }

#pragma unroll
    for (int g = 0; g < 2; g++) {
        float lrun = (g == 0) ? plsum0 : plsum1;
        lrun += __shfl_xor(lrun, 16);
        lrun += __shfl_xor(lrun, 32);
        float iv[4];
#pragma unroll
        for (int r = 0; r < 4; r++) iv[r] = 1.0f / __shfl(lrun, hi * 4 + r, 16);
#pragma unroll
        for (int r = 0; r < 4; r++) {
            int grow = b * SS + q0 + g * 16 + hi * 4 + r;
#pragma unroll
            for (int nd = 0; nd < 4; nd++)
                ctx[(size_t)grow * HDIM + h * HD + nd * 16 + lr] =
                    f2bf(((g == 0) ? o[0][nd][r] : o[1][nd][r]) * iv[r]);
        }
    }
}

// ---------------- launch ----------------
extern "C" void kernel_launch(void* const* d_in, const int* in_sizes, int n_in,
                              void* d_out, int out_size, void* d_ws, size_t ws_size,
                              hipStream_t stream)
{
    const float* x    = (const float*)d_in[0];
    const int*   amask= (const int*)d_in[1];
    const float* Wq   = (const float*)d_in[2];
    const float* bq   = (const float*)d_in[3];
    const float* Wk   = (const float*)d_in[4];
    const float* bk   = (const float*)d_in[5];
    const float* Wv   = (const float*)d_in[6];
    const float* bv   = (const float*)d_in[7];
    const float* Wo   = (const float*)d_in[8];
    const float* bo   = (const float*)d_in[9];
    float* out = (float*)d_out;

    char* ws = (char*)d_ws;
    unsigned short* xb   = (unsigned short*)(ws);                   // 12582912
    unsigned short* wqkv = (unsigned short*)(ws + 12582912);        // 3538944
    unsigned short* wo   = (unsigned short*)(ws + 16121856);        // 1179648
    float*          biasq= (float*)(ws + 17301504);                 // 9216
    unsigned short* qb   = (unsigned short*)(ws + 17310720);        // 12582912
    unsigned short* kb   = (unsigned short*)(ws + 29893632);        // 12582912
    unsigned short* vtb  = (unsigned short*)(ws + 42476544);        // 12582912
    unsigned short* ctx  = (unsigned short*)(ws + 55059456);        // 12582912
    float*          madd = (float*)(ws + 67642368);                 // 32768 -> ends 67675136

    pack_all<<<2048, 256, 0, stream>>>(x, Wq, Wk, Wv, Wo, bq, bk, bv, amask,
                                       xb, wqkv, wo, biasq, madd);

    gemm_bt<0><<<(MROWS / 128) * (NQKV / 128), 512, 0, stream>>>(
        xb, wqkv, biasq, qb, kb, vtb, nullptr, GK, NQKV / 128);

    attn_kernel<<<(SS / 128) * NH * BB, 256, 0, stream>>>(qb, kb, vtb, madd, ctx);

    gemm_bt<1><<<(MROWS / 128) * (HDIM / 128), 512, 0, stream>>>(
        ctx, wo, bo, nullptr, nullptr, nullptr, out, GK, HDIM / 128);
}